// Round 19
// baseline (531.544 us; speedup 1.0000x reference)
//
#include <hip/hip_runtime.h>
#include <stdint.h>
#include <stddef.h>

// ---------------------------------------------------------------------------
// StyleGAN2ConvBlock on MI355X (gfx950)
// Factorization: conv(x, w*style*demod) = demod[co] * conv(x*style[ci], w)
//   demod[b][co] = rsqrt( sum_ci style[b][ci]^2 * wsq[co][ci] + 1e-8 )
// Pipeline (k_mod fused into conv0):
//   k_prep1: styles, wsq, weights -> bf16 tap-major wT[t][co][ci]
//   k_prep2: demod0/demod1
//   k_conv0: implicit-GEMM 3x3, 4 waves; A-tile (8h x 16w + halo) staged by
//            FUSED modulate (x NCHW f32 -> *style0 -> bf16 -> swizzled LDS);
//            B in 4 LDS buffers (2 pairs), 18 merged phases, 1 barrier/phase;
//            two-pass epilogue with PER-HALF nz[32] noise hoist.
//   k_conv1: same K-loop; nz[32] noise hoist epilogue, f32 out + fused to-RGB.
// ---------------------------------------------------------------------------

typedef __bf16 bf16;
typedef __bf16 bf16x8 __attribute__((ext_vector_type(8)));
typedef float  f32x4  __attribute__((ext_vector_type(4)));

#define AS1 __attribute__((address_space(1)))
#define AS3 __attribute__((address_space(3)))

// workspace layout (bytes) — total ~134.8 MB
#define OFF_A1    0ull            // 8*256*256*128 bf16 = 134217728
#define OFF_WT0   134217728ull    // 9*128*128 bf16 = 294912
#define OFF_WT1   134512640ull    // 9*64*128  bf16 = 147456
#define OFF_S0    134660096ull    // 8*128 f32
#define OFF_S1    134664192ull
#define OFF_DM0   134668288ull    // 8*128 f32
#define OFF_DM1   134672384ull    // 8*64  f32
#define OFF_WSQ0  134674432ull    // 128*128 f32
#define OFF_WSQ1  134739968ull    // 64*128 f32
#define OFF_ZP    134772736ull    // 256B zeros

static __device__ __forceinline__ void gload_lds16(const void* src, void* ldsdst) {
  // LDS dest is wave-uniform base; HW writes base + lane*16. Global src is per-lane.
  __builtin_amdgcn_global_load_lds((const AS1 void*)src, (AS3 void*)ldsdst, 16, 0, 0);
}

// ---------------------------------------------------------------------------
__global__ __launch_bounds__(256) void k_prep1(
    const float* __restrict__ cond, const float* __restrict__ cw0,
    const float* __restrict__ cw1, const float* __restrict__ w0,
    const float* __restrict__ w1, float* __restrict__ s0, float* __restrict__ s1,
    bf16* __restrict__ wt0, bf16* __restrict__ wt1,
    float* __restrict__ wsq0, float* __restrict__ wsq1, float* __restrict__ zp)
{
  int idx = blockIdx.x * 256 + threadIdx.x;
  if (idx < 2048) {            // styles: 2 x 8 x 128, dot over 512
    int which = idx >> 10; int b = (idx >> 7) & 7; int c = idx & 127;
    const float* cw = which ? cw1 : cw0;
    const float* cp = cond + b * 512;
    const float* wp = cw + c * 512;
    float acc = 0.f;
    for (int j = 0; j < 512; ++j) acc += cp[j] * wp[j];
    (which ? s1 : s0)[b * 128 + c] = acc * 0.044194173824159216f; // 1/sqrt(512)
    return;
  }
  idx -= 2048;
  if (idx < 147456) {          // wt0[t][co][ci] <- w0[co][ci][t]
    int t = idx >> 14;
    wt0[idx] = (bf16)w0[(idx & 16383) * 9 + t];
    return;
  }
  idx -= 147456;
  if (idx < 73728) {           // wt1[t][co][ci] <- w1[co][ci][t]
    int t = idx >> 13;
    wt1[idx] = (bf16)w1[(idx & 8191) * 9 + t];
    return;
  }
  idx -= 73728;
  if (idx < 16384) {           // wsq0[co*128+ci] = sum_t w0^2
    const float* p = w0 + idx * 9; float a = 0.f;
    #pragma unroll
    for (int t = 0; t < 9; ++t) a += p[t] * p[t];
    wsq0[idx] = a; return;
  }
  idx -= 16384;
  if (idx < 8192) {
    const float* p = w1 + idx * 9; float a = 0.f;
    #pragma unroll
    for (int t = 0; t < 9; ++t) a += p[t] * p[t];
    wsq1[idx] = a; return;
  }
  idx -= 8192;
  if (idx < 64) zp[idx] = 0.f; // zero page for SAME-padding staging (conv1)
}

// ---------------------------------------------------------------------------
__global__ __launch_bounds__(256) void k_prep2(
    const float* __restrict__ s0, const float* __restrict__ s1,
    const float* __restrict__ wsq0, const float* __restrict__ wsq1,
    float* __restrict__ dm0, float* __restrict__ dm1)
{
  int idx = blockIdx.x * 256 + threadIdx.x;
  if (idx < 1024) {
    int b = idx >> 7, co = idx & 127;
    const float* sp = s0 + b * 128; const float* wp = wsq0 + co * 128;
    float a = 0.f;
    for (int ci = 0; ci < 128; ++ci) { float s = sp[ci]; a += s * s * wp[ci]; }
    dm0[idx] = rsqrtf(a + 1e-8f);
  } else if (idx < 1536) {
    int j = idx - 1024; int b = j >> 6, co = j & 63;
    const float* sp = s1 + b * 128; const float* wp = wsq1 + co * 128;
    float a = 0.f;
    for (int ci = 0; ci < 128; ++ci) { float s = sp[ci]; a += s * s * wp[ci]; }
    dm1[j] = rsqrtf(a + 1e-8f);
  }
}

constexpr int cDY[9] = {0,0,0,1,1,1,2,2,2};
constexpr int cDX[9] = {0,1,2,0,1,2,0,1,2};

// ---------------------------------------------------------------------------
// Stage A halo tile 10x18 px x 128ci into LDS via global_load_lds (bf16 NHWC
// source; used by conv1). Chunk slot XOR-swizzled by pin&7 via source index.
static __device__ __forceinline__ void stage_tileA(
    const bf16* __restrict__ src, const bf16* __restrict__ zp, char* Abase,
    int b, int h0, int w0p, int wave, int lane)
{
  #pragma unroll
  for (int i = 0; i < 12; ++i) {
    int g = wave + (i << 2);
    if (g < 45) {
      int pin = (g << 2) + (lane >> 4); int j = lane & 15;
      int r = pin / 18; int c = pin - r * 18;
      int gh = h0 - 1 + r, gw = w0p - 1 + c;
      const bf16* s;
      if (((unsigned)gh < 256u) & ((unsigned)gw < 256u))
        s = src + ((((size_t)(b << 16)) + (gh << 8) + gw) << 7) + ((j ^ (pin & 7)) << 3);
      else
        s = zp;  // SAME padding -> zeros
      gload_lds16(s, Abase + (size_t)g * 1024);
    }
  }
}

// ---------------------------------------------------------------------------
// conv0: Cin=128 -> Cout=128.  Block 8h x 16w x 128co, 4 waves.
// FUSED A-staging: read x (NCHW f32), *style0, cvt bf16, ds_write swizzled.
// 18 merged phases (2 K-steps each), 1 vmcnt(0)+s_barrier per phase.
// Two-pass epilogue zl[64][129] with per-half nz[32] noise hoist.
// Dynamic LDS 78848 = A 46080 | B00 8192 | B01 8192 | B10 8192 | B11 8192.
__global__ __launch_bounds__(256, 2) void k_conv0(
    const float* __restrict__ x, const bf16* __restrict__ wt,
    const float* __restrict__ s0, const float* __restrict__ dm,
    const float* __restrict__ bias, const float* __restrict__ noise,
    const float* __restrict__ nsc, const float* __restrict__ s1,
    bf16* __restrict__ A1)
{
  extern __shared__ __align__(16) char lds[];
  char* Abase = lds;
  char* Bp[4] = { lds + 46080, lds + 54272, lds + 62464, lds + 70656 };

  int bid = blockIdx.x;
  int wg = (bid & 7) * 512 + (bid >> 3);   // bijective XCD swizzle (4096 % 8 == 0)
  int b = wg >> 9; int rem = wg & 511;
  int h0 = (rem >> 4) << 3; int w0p = (rem & 15) << 4;
  int tid = threadIdx.x; int wave = tid >> 6; int lane = tid & 63;

  auto stageB = [&](int s, char* dst) {   // 2 gloads/wave -> 8KB tile
    const int t = s >> 2, ci = (s & 3) << 5;
    #pragma unroll
    for (int i = 0; i < 2; ++i) {
      int co_base = (wave << 4) + (i << 6);
      int co = co_base + (lane >> 2);
      int kgs = (lane & 3) ^ ((co >> 1) & 3);
      gload_lds16(wt + ((size_t)t << 14) + co * 128 + ci + (kgs << 3),
                  dst + co_base * 64);
    }
  };

  // issue B(0), B(1) first so their latency hides under A-staging VALU work
  stageB(0, Bp[0]);
  stageB(1, Bp[1]);

  // ---- fused modulate + transpose A staging (180 pins x 16 chunks) ----
  {
    const float* sb = s0 + (b << 7);
    for (int task = tid; task < 2880; task += 256) {
      int j = task / 180; int pin = task - j * 180;  // j = ci chunk, pin = pixel
      int r = pin / 18;  int c = pin - r * 18;
      int gh = h0 - 1 + r, gw = w0p - 1 + c;
      bf16x8 v;
      if (((unsigned)gh < 256u) & ((unsigned)gw < 256u)) {
        const float* xp = x + (((size_t)((b << 7) + (j << 3))) << 16) + (gh << 8) + gw;
        #pragma unroll
        for (int i = 0; i < 8; ++i)
          v[i] = (bf16)(xp[(size_t)i << 16] * sb[(j << 3) + i]);
      } else {
        #pragma unroll
        for (int i = 0; i < 8; ++i) v[i] = (bf16)0.f;  // SAME padding
      }
      *(bf16x8*)(Abase + pin * 256 + ((j ^ (pin & 7)) << 4)) = v;
    }
  }
  __syncthreads();   // drains ds_writes (lgkm) + B gloads (vmcnt)

  int m16 = lane & 15, kg = lane >> 4;
  int pb = (wave >> 1) << 6, cb = (wave & 1) << 6;
  int basePin[4];
  #pragma unroll
  for (int mr = 0; mr < 4; ++mr)
    basePin[mr] = ((pb >> 4) + mr) * 18 + m16;

  f32x4 acc[4][4] = {};
  #pragma unroll
  for (int p = 0; p < 18; ++p) {
    // stage next phase's B pair (latency spans this whole phase)
    if (p + 1 < 18) {
      stageB(2 * (p + 1),     Bp[((p + 1) & 1) * 2]);
      stageB(2 * (p + 1) + 1, Bp[((p + 1) & 1) * 2 + 1]);
    }
    #pragma unroll
    for (int sub = 0; sub < 2; ++sub) {
      const int s = 2 * p + sub;
      char* Bcur = Bp[(p & 1) * 2 + sub];
      const int t = s >> 2, c4 = s & 3;
      const int dy = cDY[t], dx = cDX[t];
      bf16x8 a[4], bwv[4];
      #pragma unroll
      for (int nr = 0; nr < 4; ++nr) {
        int co = cb + nr * 16 + m16;
        int slot = kg ^ ((co >> 1) & 3);
        bwv[nr] = *(const bf16x8*)(Bcur + co * 64 + (slot << 4));
      }
      #pragma unroll
      for (int mr = 0; mr < 4; ++mr) {
        int pin = basePin[mr] + dy * 18 + dx;
        int cc = (c4 << 2) + kg;
        a[mr] = *(const bf16x8*)(Abase + pin * 256 + ((cc ^ (pin & 7)) << 4));
      }
      __builtin_amdgcn_s_setprio(1);
      #pragma unroll
      for (int mr = 0; mr < 4; ++mr)
        #pragma unroll
        for (int nr = 0; nr < 4; ++nr)
          acc[mr][nr] = __builtin_amdgcn_mfma_f32_16x16x32_bf16(
              a[mr], bwv[nr], acc[mr][nr], 0, 0, 0);
      __builtin_amdgcn_s_setprio(0);
    }
    if (p < 17) {  // next pair landed (issued a full phase ago)
      asm volatile("s_waitcnt vmcnt(0)" ::: "memory");
      __builtin_amdgcn_s_barrier();
    }
  }
  __syncthreads();

  // ---- two-pass epilogue, zl = f32 [64][129], per-half nz[32] hoist ----
  float* zl = (float*)lds;
  #pragma unroll
  for (int half = 0; half < 2; ++half) {
    // hoist this half's 32 noise loads BEFORE the acc->LDS transpose;
    // HBM latency hides under E1 writes + barrier.
    float nz[32];
    #pragma unroll
    for (int it = 0; it < 32; ++it) {
      int idx = it * 256 + tid; int co = idx >> 6; int p6 = idx & 63;
      int gh = h0 + (half << 2) + (p6 >> 4), gw = w0p + (p6 & 15);
      nz[it] = noise[(((size_t)((b << 7) + co)) << 16) + (gh << 8) + gw];
    }
    if ((wave >> 1) == half) {    // waves owning pixel half (pb == half*64)
      #pragma unroll
      for (int nr = 0; nr < 4; ++nr) {
        int co = cb + nr * 16 + m16;
        float d = dm[(b << 7) + co], bb = bias[co];
        #pragma unroll
        for (int mr = 0; mr < 4; ++mr) {
          int p0 = mr * 16 + (kg << 2);
          #pragma unroll
          for (int r = 0; r < 4; ++r)
            zl[(p0 + r) * 129 + co] = acc[mr][nr][r] * d + bb;
        }
      }
    }
    __syncthreads();
    // E2: add noise (registers), * style1 — no global reads
    #pragma unroll
    for (int it = 0; it < 32; ++it) {
      int idx = it * 256 + tid; int co = idx >> 6; int p6 = idx & 63;
      float y = zl[p6 * 129 + co] + nz[it] * nsc[co];
      zl[p6 * 129 + co] = y * s1[(b << 7) + co];
    }
    __syncthreads();
    // E3: pixel-major pack -> bf16 NHWC store
    #pragma unroll
    for (int it = 0; it < 4; ++it) {
      int idx = it * 256 + tid; int p6 = idx >> 4; int ch = idx & 15;
      int gh = h0 + (half << 2) + (p6 >> 4), gw = w0p + (p6 & 15);
      const float* zpt = zl + p6 * 129 + (ch << 3);
      bf16x8 v;
      #pragma unroll
      for (int i = 0; i < 8; ++i) v[i] = (bf16)zpt[i];
      *(bf16x8*)(A1 + ((((size_t)(b << 16)) + (gh << 8) + gw) << 7) + (ch << 3)) = v;
    }
    __syncthreads();
  }
}

// ---------------------------------------------------------------------------
// conv1: Cin=128 -> Cout=64.  Same 18-phase structure; B bufs 4KB.
// Static LDS 62464. nz[32]-hoist epilogue; f32 out + fused to-RGB.
__global__ __launch_bounds__(256, 2) void k_conv1(
    const bf16* __restrict__ A1, const bf16* __restrict__ wt,
    const float* __restrict__ dm, const float* __restrict__ bias,
    const float* __restrict__ noise, const float* __restrict__ nsc,
    const float* __restrict__ rgbw, const float* __restrict__ rgbb,
    const bf16* __restrict__ zp, float* __restrict__ out, float* __restrict__ rgb)
{
  __shared__ alignas(16) char lds[62464]; // A 46080 | 4 x 4096
  char* Abase = lds;
  char* Bp[4] = { lds + 46080, lds + 50176, lds + 54272, lds + 58368 };

  int bid = blockIdx.x;
  int wg = (bid & 7) * 512 + (bid >> 3);
  int b = wg >> 9; int rem = wg & 511;
  int h0 = (rem >> 4) << 3; int w0p = (rem & 15) << 4;
  int tid = threadIdx.x; int wave = tid >> 6; int lane = tid & 63;

  auto stageB = [&](int s, char* dst) {   // 1 gload/wave -> 4KB tile
    const int t = s >> 2, ci = (s & 3) << 5;
    int co_base = wave << 4;
    int co = co_base + (lane >> 2);
    int kgs = (lane & 3) ^ ((co >> 1) & 3);
    gload_lds16(wt + ((size_t)t << 13) + co * 128 + ci + (kgs << 3),
                dst + co_base * 64);
  };

  stage_tileA(A1, zp, Abase, b, h0, w0p, wave, lane);
  stageB(0, Bp[0]);
  stageB(1, Bp[1]);
  asm volatile("s_waitcnt vmcnt(0)" ::: "memory");
  __builtin_amdgcn_s_barrier();

  int m16 = lane & 15, kg = lane >> 4;
  int pb = (wave >> 1) << 6, cb = (wave & 1) << 5;
  int basePin[4];
  #pragma unroll
  for (int mr = 0; mr < 4; ++mr)
    basePin[mr] = ((pb >> 4) + mr) * 18 + m16;

  f32x4 acc[4][2] = {};
  #pragma unroll
  for (int p = 0; p < 18; ++p) {
    if (p + 1 < 18) {
      stageB(2 * (p + 1),     Bp[((p + 1) & 1) * 2]);
      stageB(2 * (p + 1) + 1, Bp[((p + 1) & 1) * 2 + 1]);
    }
    #pragma unroll
    for (int sub = 0; sub < 2; ++sub) {
      const int s = 2 * p + sub;
      char* Bcur = Bp[(p & 1) * 2 + sub];
      const int t = s >> 2, c4 = s & 3;
      const int dy = cDY[t], dx = cDX[t];
      bf16x8 a[4], bwv[2];
      #pragma unroll
      for (int nr = 0; nr < 2; ++nr) {
        int co = cb + nr * 16 + m16;
        int slot = kg ^ ((co >> 1) & 3);
        bwv[nr] = *(const bf16x8*)(Bcur + co * 64 + (slot << 4));
      }
      #pragma unroll
      for (int mr = 0; mr < 4; ++mr) {
        int pin = basePin[mr] + dy * 18 + dx;
        int cc = (c4 << 2) + kg;
        a[mr] = *(const bf16x8*)(Abase + pin * 256 + ((cc ^ (pin & 7)) << 4));
      }
      __builtin_amdgcn_s_setprio(1);
      #pragma unroll
      for (int mr = 0; mr < 4; ++mr)
        #pragma unroll
        for (int nr = 0; nr < 2; ++nr)
          acc[mr][nr] = __builtin_amdgcn_mfma_f32_16x16x32_bf16(
              a[mr], bwv[nr], acc[mr][nr], 0, 0, 0);
      __builtin_amdgcn_s_setprio(0);
    }
    if (p < 17) {
      asm volatile("s_waitcnt vmcnt(0)" ::: "memory");
      __builtin_amdgcn_s_barrier();
    }
  }
  __syncthreads();

  // ---- pipelined epilogue (nz[32] hoist; HBM latency hides under E1) ----
  float nz[32];
  #pragma unroll
  for (int it = 0; it < 32; ++it) {
    int idx = it * 256 + tid; int co = idx >> 7; int px = idx & 127;
    int gh = h0 + (px >> 4), gw = w0p + (px & 15);
    nz[it] = noise[(((size_t)((b << 6) + co)) << 16) + (gh << 8) + gw];
  }
  float* zl = (float*)lds; // [128][65] padded f32 = 33280 <= 62464
  #pragma unroll
  for (int nr = 0; nr < 2; ++nr) {
    int co = cb + nr * 16 + m16;
    float d = dm[(b << 6) + co], bb = bias[co];
    #pragma unroll
    for (int mr = 0; mr < 4; ++mr) {
      int p0 = pb + mr * 16 + (kg << 2);
      #pragma unroll
      for (int r = 0; r < 4; ++r)
        zl[(p0 + r) * 65 + co] = acc[mr][nr][r] * d + bb;
    }
  }
  __syncthreads();
  // E2: noise add + store out (coalesced NCHW, no global reads)
  #pragma unroll
  for (int it = 0; it < 32; ++it) {
    int idx = it * 256 + tid; int co = idx >> 7; int px = idx & 127;
    int gh = h0 + (px >> 4), gw = w0p + (px & 15);
    size_t go = (((size_t)((b << 6) + co)) << 16) + (gh << 8) + gw;
    float y = zl[px * 65 + co] + nz[it] * nsc[co];
    zl[px * 65 + co] = y;
    out[go] = y;
  }
  __syncthreads();
  // fused to-RGB: 128 threads own one pixel each, reduce 64 channels
  if (tid < 128) {
    int px = tid; int gh = h0 + (px >> 4), gw = w0p + (px & 15);
    float r0 = rgbb[0], r1 = rgbb[1], r2 = rgbb[2];
    for (int co = 0; co < 64; ++co) {
      float v = zl[px * 65 + co];
      r0 += v * rgbw[co]; r1 += v * rgbw[64 + co]; r2 += v * rgbw[128 + co];
    }
    size_t base = (((size_t)(b * 3)) << 16) + (gh << 8) + gw;
    rgb[base] = r0; rgb[base + (1 << 16)] = r1; rgb[base + (2 << 16)] = r2;
  }
}

// ---------------------------------------------------------------------------
extern "C" void kernel_launch(void* const* d_in, const int* in_sizes, int n_in,
                              void* d_out, int out_size, void* d_ws, size_t ws_size,
                              hipStream_t stream)
{
  const float* x      = (const float*)d_in[0];
  const float* cond   = (const float*)d_in[1];
  const float* cw0    = (const float*)d_in[2];
  const float* cw1    = (const float*)d_in[3];
  const float* w0     = (const float*)d_in[4];
  const float* b0     = (const float*)d_in[5];
  const float* w1     = (const float*)d_in[6];
  const float* b1     = (const float*)d_in[7];
  const float* ns0    = (const float*)d_in[8];
  const float* ns1    = (const float*)d_in[9];
  const float* noise0 = (const float*)d_in[10];
  const float* noise1 = (const float*)d_in[11];
  const float* rgbw   = (const float*)d_in[12];
  const float* rgbb   = (const float*)d_in[13];

  char* ws = (char*)d_ws;  // needs ~134.8 MB
  bf16*  A1   = (bf16*)(ws + OFF_A1);
  bf16*  WT0  = (bf16*)(ws + OFF_WT0);
  bf16*  WT1  = (bf16*)(ws + OFF_WT1);
  float* S0   = (float*)(ws + OFF_S0);
  float* S1   = (float*)(ws + OFF_S1);
  float* DM0  = (float*)(ws + OFF_DM0);
  float* DM1  = (float*)(ws + OFF_DM1);
  float* WSQ0 = (float*)(ws + OFF_WSQ0);
  float* WSQ1 = (float*)(ws + OFF_WSQ1);
  float* ZP   = (float*)(ws + OFF_ZP);

  float* out = (float*)d_out;
  float* rgb = out + 33554432; // 8*64*256*256

  // opt-in to >64KB dynamic LDS for conv0 (attribute call, not a stream op)
  hipFuncSetAttribute((const void*)k_conv0,
                      hipFuncAttributeMaxDynamicSharedMemorySize, 78848);

  k_prep1<<<dim3(969), dim3(256), 0, stream>>>(cond, cw0, cw1, w0, w1,
                                               S0, S1, WT0, WT1, WSQ0, WSQ1, ZP);
  k_prep2<<<dim3(6), dim3(256), 0, stream>>>(S0, S1, WSQ0, WSQ1, DM0, DM1);
  k_conv0<<<dim3(4096), dim3(256), 78848, stream>>>(x, WT0, S0, DM0, b0, noise0,
                                                    ns0, S1, A1);
  k_conv1<<<dim3(4096), dim3(256), 0, stream>>>(A1, WT1, DM1, b1, noise1, ns1,
                                                rgbw, rgbb, (const bf16*)ZP, out, rgb);
}

// Round 20
// 454.701 us; speedup vs baseline: 1.1690x; 1.1690x over previous
//
#include <hip/hip_runtime.h>
#include <stdint.h>
#include <stddef.h>

// ---------------------------------------------------------------------------
// StyleGAN2ConvBlock on MI355X (gfx950) — FINAL (r18 winner, 456.6 us)
// Factorization: conv(x, w*style*demod) = demod[co] * conv(x*style[ci], w)
//   demod[b][co] = rsqrt( sum_ci style[b][ci]^2 * wsq[co][ci] + 1e-8 )
// Pipeline (k_mod fused into conv0):
//   k_prep1: styles, wsq, weights -> bf16 tap-major wT[t][co][ci]
//   k_prep2: demod0/demod1
//   k_conv0: implicit-GEMM 3x3, 4 waves; A-tile (8h x 16w + halo) staged by
//            FUSED modulate (x NCHW f32 -> *style0 -> bf16 -> swizzled LDS);
//            B in 4 LDS buffers (2 pairs), 18 merged phases, 1 barrier/phase;
//            two-pass epilogue (no reg hoist — conv0 has no VGPR headroom).
//   k_conv1: same K-loop; nz[32] noise hoist epilogue, f32 out + fused to-RGB.
// ---------------------------------------------------------------------------

typedef __bf16 bf16;
typedef __bf16 bf16x8 __attribute__((ext_vector_type(8)));
typedef float  f32x4  __attribute__((ext_vector_type(4)));

#define AS1 __attribute__((address_space(1)))
#define AS3 __attribute__((address_space(3)))

// workspace layout (bytes) — total ~134.8 MB
#define OFF_A1    0ull            // 8*256*256*128 bf16 = 134217728
#define OFF_WT0   134217728ull    // 9*128*128 bf16 = 294912
#define OFF_WT1   134512640ull    // 9*64*128  bf16 = 147456
#define OFF_S0    134660096ull    // 8*128 f32
#define OFF_S1    134664192ull
#define OFF_DM0   134668288ull    // 8*128 f32
#define OFF_DM1   134672384ull    // 8*64  f32
#define OFF_WSQ0  134674432ull    // 128*128 f32
#define OFF_WSQ1  134739968ull    // 64*128 f32
#define OFF_ZP    134772736ull    // 256B zeros

static __device__ __forceinline__ void gload_lds16(const void* src, void* ldsdst) {
  // LDS dest is wave-uniform base; HW writes base + lane*16. Global src is per-lane.
  __builtin_amdgcn_global_load_lds((const AS1 void*)src, (AS3 void*)ldsdst, 16, 0, 0);
}

// ---------------------------------------------------------------------------
__global__ __launch_bounds__(256) void k_prep1(
    const float* __restrict__ cond, const float* __restrict__ cw0,
    const float* __restrict__ cw1, const float* __restrict__ w0,
    const float* __restrict__ w1, float* __restrict__ s0, float* __restrict__ s1,
    bf16* __restrict__ wt0, bf16* __restrict__ wt1,
    float* __restrict__ wsq0, float* __restrict__ wsq1, float* __restrict__ zp)
{
  int idx = blockIdx.x * 256 + threadIdx.x;
  if (idx < 2048) {            // styles: 2 x 8 x 128, dot over 512
    int which = idx >> 10; int b = (idx >> 7) & 7; int c = idx & 127;
    const float* cw = which ? cw1 : cw0;
    const float* cp = cond + b * 512;
    const float* wp = cw + c * 512;
    float acc = 0.f;
    for (int j = 0; j < 512; ++j) acc += cp[j] * wp[j];
    (which ? s1 : s0)[b * 128 + c] = acc * 0.044194173824159216f; // 1/sqrt(512)
    return;
  }
  idx -= 2048;
  if (idx < 147456) {          // wt0[t][co][ci] <- w0[co][ci][t]
    int t = idx >> 14;
    wt0[idx] = (bf16)w0[(idx & 16383) * 9 + t];
    return;
  }
  idx -= 147456;
  if (idx < 73728) {           // wt1[t][co][ci] <- w1[co][ci][t]
    int t = idx >> 13;
    wt1[idx] = (bf16)w1[(idx & 8191) * 9 + t];
    return;
  }
  idx -= 73728;
  if (idx < 16384) {           // wsq0[co*128+ci] = sum_t w0^2
    const float* p = w0 + idx * 9; float a = 0.f;
    #pragma unroll
    for (int t = 0; t < 9; ++t) a += p[t] * p[t];
    wsq0[idx] = a; return;
  }
  idx -= 16384;
  if (idx < 8192) {
    const float* p = w1 + idx * 9; float a = 0.f;
    #pragma unroll
    for (int t = 0; t < 9; ++t) a += p[t] * p[t];
    wsq1[idx] = a; return;
  }
  idx -= 8192;
  if (idx < 64) zp[idx] = 0.f; // zero page for SAME-padding staging (conv1)
}

// ---------------------------------------------------------------------------
__global__ __launch_bounds__(256) void k_prep2(
    const float* __restrict__ s0, const float* __restrict__ s1,
    const float* __restrict__ wsq0, const float* __restrict__ wsq1,
    float* __restrict__ dm0, float* __restrict__ dm1)
{
  int idx = blockIdx.x * 256 + threadIdx.x;
  if (idx < 1024) {
    int b = idx >> 7, co = idx & 127;
    const float* sp = s0 + b * 128; const float* wp = wsq0 + co * 128;
    float a = 0.f;
    for (int ci = 0; ci < 128; ++ci) { float s = sp[ci]; a += s * s * wp[ci]; }
    dm0[idx] = rsqrtf(a + 1e-8f);
  } else if (idx < 1536) {
    int j = idx - 1024; int b = j >> 6, co = j & 63;
    const float* sp = s1 + b * 128; const float* wp = wsq1 + co * 128;
    float a = 0.f;
    for (int ci = 0; ci < 128; ++ci) { float s = sp[ci]; a += s * s * wp[ci]; }
    dm1[j] = rsqrtf(a + 1e-8f);
  }
}

constexpr int cDY[9] = {0,0,0,1,1,1,2,2,2};
constexpr int cDX[9] = {0,1,2,0,1,2,0,1,2};

// ---------------------------------------------------------------------------
// Stage A halo tile 10x18 px x 128ci into LDS via global_load_lds (bf16 NHWC
// source; used by conv1). Chunk slot XOR-swizzled by pin&7 via source index.
static __device__ __forceinline__ void stage_tileA(
    const bf16* __restrict__ src, const bf16* __restrict__ zp, char* Abase,
    int b, int h0, int w0p, int wave, int lane)
{
  #pragma unroll
  for (int i = 0; i < 12; ++i) {
    int g = wave + (i << 2);
    if (g < 45) {
      int pin = (g << 2) + (lane >> 4); int j = lane & 15;
      int r = pin / 18; int c = pin - r * 18;
      int gh = h0 - 1 + r, gw = w0p - 1 + c;
      const bf16* s;
      if (((unsigned)gh < 256u) & ((unsigned)gw < 256u))
        s = src + ((((size_t)(b << 16)) + (gh << 8) + gw) << 7) + ((j ^ (pin & 7)) << 3);
      else
        s = zp;  // SAME padding -> zeros
      gload_lds16(s, Abase + (size_t)g * 1024);
    }
  }
}

// ---------------------------------------------------------------------------
// conv0: Cin=128 -> Cout=128.  Block 8h x 16w x 128co, 4 waves.
// FUSED A-staging: read x (NCHW f32), *style0, cvt bf16, ds_write swizzled.
// 18 merged phases (2 K-steps each), 1 vmcnt(0)+s_barrier per phase.
// Two-pass epilogue zl[64][129].
// Dynamic LDS 78848 = A 46080 | B00 8192 | B01 8192 | B10 8192 | B11 8192.
__global__ __launch_bounds__(256, 2) void k_conv0(
    const float* __restrict__ x, const bf16* __restrict__ wt,
    const float* __restrict__ s0, const float* __restrict__ dm,
    const float* __restrict__ bias, const float* __restrict__ noise,
    const float* __restrict__ nsc, const float* __restrict__ s1,
    bf16* __restrict__ A1)
{
  extern __shared__ __align__(16) char lds[];
  char* Abase = lds;
  char* Bp[4] = { lds + 46080, lds + 54272, lds + 62464, lds + 70656 };

  int bid = blockIdx.x;
  int wg = (bid & 7) * 512 + (bid >> 3);   // bijective XCD swizzle (4096 % 8 == 0)
  int b = wg >> 9; int rem = wg & 511;
  int h0 = (rem >> 4) << 3; int w0p = (rem & 15) << 4;
  int tid = threadIdx.x; int wave = tid >> 6; int lane = tid & 63;

  auto stageB = [&](int s, char* dst) {   // 2 gloads/wave -> 8KB tile
    const int t = s >> 2, ci = (s & 3) << 5;
    #pragma unroll
    for (int i = 0; i < 2; ++i) {
      int co_base = (wave << 4) + (i << 6);
      int co = co_base + (lane >> 2);
      int kgs = (lane & 3) ^ ((co >> 1) & 3);
      gload_lds16(wt + ((size_t)t << 14) + co * 128 + ci + (kgs << 3),
                  dst + co_base * 64);
    }
  };

  // issue B(0), B(1) first so their latency hides under A-staging VALU work
  stageB(0, Bp[0]);
  stageB(1, Bp[1]);

  // ---- fused modulate + transpose A staging (180 pins x 16 chunks) ----
  {
    const float* sb = s0 + (b << 7);
    for (int task = tid; task < 2880; task += 256) {
      int j = task / 180; int pin = task - j * 180;  // j = ci chunk, pin = pixel
      int r = pin / 18;  int c = pin - r * 18;
      int gh = h0 - 1 + r, gw = w0p - 1 + c;
      bf16x8 v;
      if (((unsigned)gh < 256u) & ((unsigned)gw < 256u)) {
        const float* xp = x + (((size_t)((b << 7) + (j << 3))) << 16) + (gh << 8) + gw;
        #pragma unroll
        for (int i = 0; i < 8; ++i)
          v[i] = (bf16)(xp[(size_t)i << 16] * sb[(j << 3) + i]);
      } else {
        #pragma unroll
        for (int i = 0; i < 8; ++i) v[i] = (bf16)0.f;  // SAME padding
      }
      *(bf16x8*)(Abase + pin * 256 + ((j ^ (pin & 7)) << 4)) = v;
    }
  }
  __syncthreads();   // drains ds_writes (lgkm) + B gloads (vmcnt)

  int m16 = lane & 15, kg = lane >> 4;
  int pb = (wave >> 1) << 6, cb = (wave & 1) << 6;
  int basePin[4];
  #pragma unroll
  for (int mr = 0; mr < 4; ++mr)
    basePin[mr] = ((pb >> 4) + mr) * 18 + m16;

  f32x4 acc[4][4] = {};
  #pragma unroll
  for (int p = 0; p < 18; ++p) {
    // stage next phase's B pair (latency spans this whole phase)
    if (p + 1 < 18) {
      stageB(2 * (p + 1),     Bp[((p + 1) & 1) * 2]);
      stageB(2 * (p + 1) + 1, Bp[((p + 1) & 1) * 2 + 1]);
    }
    #pragma unroll
    for (int sub = 0; sub < 2; ++sub) {
      const int s = 2 * p + sub;
      char* Bcur = Bp[(p & 1) * 2 + sub];
      const int t = s >> 2, c4 = s & 3;
      const int dy = cDY[t], dx = cDX[t];
      bf16x8 a[4], bwv[4];
      #pragma unroll
      for (int nr = 0; nr < 4; ++nr) {
        int co = cb + nr * 16 + m16;
        int slot = kg ^ ((co >> 1) & 3);
        bwv[nr] = *(const bf16x8*)(Bcur + co * 64 + (slot << 4));
      }
      #pragma unroll
      for (int mr = 0; mr < 4; ++mr) {
        int pin = basePin[mr] + dy * 18 + dx;
        int cc = (c4 << 2) + kg;
        a[mr] = *(const bf16x8*)(Abase + pin * 256 + ((cc ^ (pin & 7)) << 4));
      }
      __builtin_amdgcn_s_setprio(1);
      #pragma unroll
      for (int mr = 0; mr < 4; ++mr)
        #pragma unroll
        for (int nr = 0; nr < 4; ++nr)
          acc[mr][nr] = __builtin_amdgcn_mfma_f32_16x16x32_bf16(
              a[mr], bwv[nr], acc[mr][nr], 0, 0, 0);
      __builtin_amdgcn_s_setprio(0);
    }
    if (p < 17) {  // next pair landed (issued a full phase ago)
      asm volatile("s_waitcnt vmcnt(0)" ::: "memory");
      __builtin_amdgcn_s_barrier();
    }
  }
  __syncthreads();

  // ---- two-pass epilogue, zl = f32 [64][129]
  float* zl = (float*)lds;
  #pragma unroll
  for (int half = 0; half < 2; ++half) {
    if ((wave >> 1) == half) {    // waves owning pixel half (pb == half*64)
      #pragma unroll
      for (int nr = 0; nr < 4; ++nr) {
        int co = cb + nr * 16 + m16;
        float d = dm[(b << 7) + co], bb = bias[co];
        #pragma unroll
        for (int mr = 0; mr < 4; ++mr) {
          int p0 = mr * 16 + (kg << 2);
          #pragma unroll
          for (int r = 0; r < 4; ++r)
            zl[(p0 + r) * 129 + co] = acc[mr][nr][r] * d + bb;
        }
      }
    }
    __syncthreads();
    // E2: add noise (NCHW read), * style1
    #pragma unroll 4
    for (int it = 0; it < 32; ++it) {
      int idx = it * 256 + tid; int co = idx >> 6; int p6 = idx & 63;
      int gh = h0 + (half << 2) + (p6 >> 4), gw = w0p + (p6 & 15);
      float n = noise[(((size_t)((b << 7) + co)) << 16) + (gh << 8) + gw];
      float y = zl[p6 * 129 + co] + n * nsc[co];
      zl[p6 * 129 + co] = y * s1[(b << 7) + co];
    }
    __syncthreads();
    // E3: pixel-major pack -> bf16 NHWC store
    #pragma unroll
    for (int it = 0; it < 4; ++it) {
      int idx = it * 256 + tid; int p6 = idx >> 4; int ch = idx & 15;
      int gh = h0 + (half << 2) + (p6 >> 4), gw = w0p + (p6 & 15);
      const float* zpt = zl + p6 * 129 + (ch << 3);
      bf16x8 v;
      #pragma unroll
      for (int i = 0; i < 8; ++i) v[i] = (bf16)zpt[i];
      *(bf16x8*)(A1 + ((((size_t)(b << 16)) + (gh << 8) + gw) << 7) + (ch << 3)) = v;
    }
    __syncthreads();
  }
}

// ---------------------------------------------------------------------------
// conv1: Cin=128 -> Cout=64.  Same 18-phase structure; B bufs 4KB.
// Static LDS 62464. nz[32]-hoist epilogue; f32 out + fused to-RGB.
__global__ __launch_bounds__(256, 2) void k_conv1(
    const bf16* __restrict__ A1, const bf16* __restrict__ wt,
    const float* __restrict__ dm, const float* __restrict__ bias,
    const float* __restrict__ noise, const float* __restrict__ nsc,
    const float* __restrict__ rgbw, const float* __restrict__ rgbb,
    const bf16* __restrict__ zp, float* __restrict__ out, float* __restrict__ rgb)
{
  __shared__ alignas(16) char lds[62464]; // A 46080 | 4 x 4096
  char* Abase = lds;
  char* Bp[4] = { lds + 46080, lds + 50176, lds + 54272, lds + 58368 };

  int bid = blockIdx.x;
  int wg = (bid & 7) * 512 + (bid >> 3);
  int b = wg >> 9; int rem = wg & 511;
  int h0 = (rem >> 4) << 3; int w0p = (rem & 15) << 4;
  int tid = threadIdx.x; int wave = tid >> 6; int lane = tid & 63;

  auto stageB = [&](int s, char* dst) {   // 1 gload/wave -> 4KB tile
    const int t = s >> 2, ci = (s & 3) << 5;
    int co_base = wave << 4;
    int co = co_base + (lane >> 2);
    int kgs = (lane & 3) ^ ((co >> 1) & 3);
    gload_lds16(wt + ((size_t)t << 13) + co * 128 + ci + (kgs << 3),
                dst + co_base * 64);
  };

  stage_tileA(A1, zp, Abase, b, h0, w0p, wave, lane);
  stageB(0, Bp[0]);
  stageB(1, Bp[1]);
  asm volatile("s_waitcnt vmcnt(0)" ::: "memory");
  __builtin_amdgcn_s_barrier();

  int m16 = lane & 15, kg = lane >> 4;
  int pb = (wave >> 1) << 6, cb = (wave & 1) << 5;
  int basePin[4];
  #pragma unroll
  for (int mr = 0; mr < 4; ++mr)
    basePin[mr] = ((pb >> 4) + mr) * 18 + m16;

  f32x4 acc[4][2] = {};
  #pragma unroll
  for (int p = 0; p < 18; ++p) {
    if (p + 1 < 18) {
      stageB(2 * (p + 1),     Bp[((p + 1) & 1) * 2]);
      stageB(2 * (p + 1) + 1, Bp[((p + 1) & 1) * 2 + 1]);
    }
    #pragma unroll
    for (int sub = 0; sub < 2; ++sub) {
      const int s = 2 * p + sub;
      char* Bcur = Bp[(p & 1) * 2 + sub];
      const int t = s >> 2, c4 = s & 3;
      const int dy = cDY[t], dx = cDX[t];
      bf16x8 a[4], bwv[2];
      #pragma unroll
      for (int nr = 0; nr < 2; ++nr) {
        int co = cb + nr * 16 + m16;
        int slot = kg ^ ((co >> 1) & 3);
        bwv[nr] = *(const bf16x8*)(Bcur + co * 64 + (slot << 4));
      }
      #pragma unroll
      for (int mr = 0; mr < 4; ++mr) {
        int pin = basePin[mr] + dy * 18 + dx;
        int cc = (c4 << 2) + kg;
        a[mr] = *(const bf16x8*)(Abase + pin * 256 + ((cc ^ (pin & 7)) << 4));
      }
      __builtin_amdgcn_s_setprio(1);
      #pragma unroll
      for (int mr = 0; mr < 4; ++mr)
        #pragma unroll
        for (int nr = 0; nr < 2; ++nr)
          acc[mr][nr] = __builtin_amdgcn_mfma_f32_16x16x32_bf16(
              a[mr], bwv[nr], acc[mr][nr], 0, 0, 0);
      __builtin_amdgcn_s_setprio(0);
    }
    if (p < 17) {
      asm volatile("s_waitcnt vmcnt(0)" ::: "memory");
      __builtin_amdgcn_s_barrier();
    }
  }
  __syncthreads();

  // ---- pipelined epilogue (nz[32] hoist; HBM latency hides under E1) ----
  float nz[32];
  #pragma unroll
  for (int it = 0; it < 32; ++it) {
    int idx = it * 256 + tid; int co = idx >> 7; int px = idx & 127;
    int gh = h0 + (px >> 4), gw = w0p + (px & 15);
    nz[it] = noise[(((size_t)((b << 6) + co)) << 16) + (gh << 8) + gw];
  }
  float* zl = (float*)lds; // [128][65] padded f32 = 33280 <= 62464
  #pragma unroll
  for (int nr = 0; nr < 2; ++nr) {
    int co = cb + nr * 16 + m16;
    float d = dm[(b << 6) + co], bb = bias[co];
    #pragma unroll
    for (int mr = 0; mr < 4; ++mr) {
      int p0 = pb + mr * 16 + (kg << 2);
      #pragma unroll
      for (int r = 0; r < 4; ++r)
        zl[(p0 + r) * 65 + co] = acc[mr][nr][r] * d + bb;
    }
  }
  __syncthreads();
  // E2: noise add + store out (coalesced NCHW, no global reads)
  #pragma unroll
  for (int it = 0; it < 32; ++it) {
    int idx = it * 256 + tid; int co = idx >> 7; int px = idx & 127;
    int gh = h0 + (px >> 4), gw = w0p + (px & 15);
    size_t go = (((size_t)((b << 6) + co)) << 16) + (gh << 8) + gw;
    float y = zl[px * 65 + co] + nz[it] * nsc[co];
    zl[px * 65 + co] = y;
    out[go] = y;
  }
  __syncthreads();
  // fused to-RGB: 128 threads own one pixel each, reduce 64 channels
  if (tid < 128) {
    int px = tid; int gh = h0 + (px >> 4), gw = w0p + (px & 15);
    float r0 = rgbb[0], r1 = rgbb[1], r2 = rgbb[2];
    for (int co = 0; co < 64; ++co) {
      float v = zl[px * 65 + co];
      r0 += v * rgbw[co]; r1 += v * rgbw[64 + co]; r2 += v * rgbw[128 + co];
    }
    size_t base = (((size_t)(b * 3)) << 16) + (gh << 8) + gw;
    rgb[base] = r0; rgb[base + (1 << 16)] = r1; rgb[base + (2 << 16)] = r2;
  }
}

// ---------------------------------------------------------------------------
extern "C" void kernel_launch(void* const* d_in, const int* in_sizes, int n_in,
                              void* d_out, int out_size, void* d_ws, size_t ws_size,
                              hipStream_t stream)
{
  const float* x      = (const float*)d_in[0];
  const float* cond   = (const float*)d_in[1];
  const float* cw0    = (const float*)d_in[2];
  const float* cw1    = (const float*)d_in[3];
  const float* w0     = (const float*)d_in[4];
  const float* b0     = (const float*)d_in[5];
  const float* w1     = (const float*)d_in[6];
  const float* b1     = (const float*)d_in[7];
  const float* ns0    = (const float*)d_in[8];
  const float* ns1    = (const float*)d_in[9];
  const float* noise0 = (const float*)d_in[10];
  const float* noise1 = (const float*)d_in[11];
  const float* rgbw   = (const float*)d_in[12];
  const float* rgbb   = (const float*)d_in[13];

  char* ws = (char*)d_ws;  // needs ~134.8 MB
  bf16*  A1   = (bf16*)(ws + OFF_A1);
  bf16*  WT0  = (bf16*)(ws + OFF_WT0);
  bf16*  WT1  = (bf16*)(ws + OFF_WT1);
  float* S0   = (float*)(ws + OFF_S0);
  float* S1   = (float*)(ws + OFF_S1);
  float* DM0  = (float*)(ws + OFF_DM0);
  float* DM1  = (float*)(ws + OFF_DM1);
  float* WSQ0 = (float*)(ws + OFF_WSQ0);
  float* WSQ1 = (float*)(ws + OFF_WSQ1);
  float* ZP   = (float*)(ws + OFF_ZP);

  float* out = (float*)d_out;
  float* rgb = out + 33554432; // 8*64*256*256

  // opt-in to >64KB dynamic LDS for conv0 (attribute call, not a stream op)
  hipFuncSetAttribute((const void*)k_conv0,
                      hipFuncAttributeMaxDynamicSharedMemorySize, 78848);

  k_prep1<<<dim3(969), dim3(256), 0, stream>>>(cond, cw0, cw1, w0, w1,
                                               S0, S1, WT0, WT1, WSQ0, WSQ1, ZP);
  k_prep2<<<dim3(6), dim3(256), 0, stream>>>(S0, S1, WSQ0, WSQ1, DM0, DM1);
  k_conv0<<<dim3(4096), dim3(256), 78848, stream>>>(x, WT0, S0, DM0, b0, noise0,
                                                    ns0, S1, A1);
  k_conv1<<<dim3(4096), dim3(256), 0, stream>>>(A1, WT1, DM1, b1, noise1, ns1,
                                                rgbw, rgbb, (const bf16*)ZP, out, rgb);
}